// Round 1
// baseline (328.522 us; speedup 1.0000x reference)
//
#include <hip/hip_runtime.h>
#include <math.h>

// Problem: gather c2[:,:,7,7] (100x128) and c3[:,:,3,3] (100x256), compute
//   p = (||tm1-vmask1|| + ||tm2-vmask2||) / 38400
//   m1 = kth_smallest(tm1, 6399), m2 = kth_smallest(tm2, 12799)   (torch lower median)
//   q = (||(tm1<m1?0:1)-amask1|| + ||(tm2<m2?0:1)-amask2||) / 384
// out = [p, q]  (2 fp32)
//
// ws layout (floats): W1[0..12800) gathered tm1, W2[12800..38400) gathered tm2,
//                     partial[38400..38550) per-block sumsq partials.

#define N1 12800
#define N2 25600
#define K1 6399   // (12800-1)/2
#define K2 12799  // (25600-1)/2

__device__ __forceinline__ unsigned fkey(float f) {
    unsigned u = __float_as_uint(f);
    // order-preserving float -> uint map
    return (u & 0x80000000u) ? ~u : (u | 0x80000000u);
}
__device__ __forceinline__ float fkey_inv(unsigned u) {
    return (u & 0x80000000u) ? __uint_as_float(u & 0x7FFFFFFFu)
                             : __uint_as_float(~u);
}

// Block-wide sum; result valid in thread 0. red[] must hold >=16 floats.
__device__ __forceinline__ float block_reduce(float v, float* red) {
    const int lane = threadIdx.x & 63;
    const int wid  = threadIdx.x >> 6;
    const int nw   = (blockDim.x + 63) >> 6;
#pragma unroll
    for (int o = 32; o > 0; o >>= 1) v += __shfl_down(v, o, 64);
    if (lane == 0) red[wid] = v;
    __syncthreads();
    if (wid == 0) {
        v = (lane < nw) ? red[lane] : 0.f;
#pragma unroll
        for (int o = 8; o > 0; o >>= 1) v += __shfl_down(v, o, 64);
    }
    __syncthreads();
    return v;
}

// Kernel 1: exactly 150 blocks x 256 threads = 38400 threads.
// Blocks [0,50): tm1 gather; blocks [50,150): tm2 gather.
__global__ __launch_bounds__(256) void gather_kernel(
    const float* __restrict__ c2, const float* __restrict__ c3,
    const float* __restrict__ vm1, const float* __restrict__ vm2,
    float* __restrict__ W1, float* __restrict__ W2,
    float* __restrict__ partial)
{
    __shared__ float red[16];
    int g = blockIdx.x * 256 + threadIdx.x;
    float d;
    if (g < N1) {
        float v = c2[(size_t)g * 3136 + 399];   // [b,c,7,7]: 7*56+7 = 399
        W1[g] = v;
        d = v - vm1[g];
    } else {
        int j = g - N1;
        float v = c3[(size_t)j * 784 + 87];     // [b,c,3,3]: 3*28+3 = 87
        W2[j] = v;
        d = v - vm2[j];
    }
    float ss = block_reduce(d * d, red);
    if (threadIdx.x == 0) partial[blockIdx.x] = ss;
}

// Block-cooperative exact k-th smallest via 4x 8-bit radix passes.
// All threads return the selected value.
__device__ float radix_select(const float* __restrict__ W, int n, int k,
                              unsigned* hist, unsigned* s_pm, int* s_kk)
{
    __syncthreads();  // protect s_pm/s_kk from previous use
    if (threadIdx.x == 0) { s_pm[0] = 0u; s_pm[1] = 0u; *s_kk = k; }
    __syncthreads();
    for (int pass = 0; pass < 4; ++pass) {
        const int shift = 24 - pass * 8;
        for (int i = threadIdx.x; i < 256; i += blockDim.x) hist[i] = 0u;
        __syncthreads();
        const unsigned prefix = s_pm[0], mask = s_pm[1];
        for (int i = threadIdx.x; i < n; i += blockDim.x) {
            unsigned u = fkey(W[i]);
            if ((u & mask) == prefix)
                atomicAdd(&hist[(u >> shift) & 255u], 1u);
        }
        __syncthreads();
        if (threadIdx.x == 0) {
            int kk = *s_kk;
            unsigned cum = 0; int b = 0;
            for (; b < 256; ++b) {
                unsigned c = hist[b];
                if ((unsigned)kk < cum + c) break;
                cum += c;
            }
            *s_kk = kk - (int)cum;
            s_pm[0] = prefix | ((unsigned)b << shift);
            s_pm[1] = mask | (0xFFu << shift);
        }
        __syncthreads();
    }
    float r = fkey_inv(s_pm[0]);
    __syncthreads();
    return r;
}

// Kernel 2: single block, 1024 threads. Finishes everything.
__global__ __launch_bounds__(1024) void finish_kernel(
    const float* __restrict__ W1, const float* __restrict__ W2,
    const float* __restrict__ partial,
    const float* __restrict__ am1, const float* __restrict__ am2,
    float* __restrict__ out)
{
    __shared__ unsigned hist[256];
    __shared__ unsigned s_pm[2];
    __shared__ int s_kk;
    __shared__ float red[16];

    const int t = threadIdx.x;

    // 1) finish p-sums (150 per-block partials; [0,50)->s1, [50,150)->s2)
    float a = (t < 50) ? partial[t] : 0.f;
    float b = (t >= 50 && t < 150) ? partial[t] : 0.f;
    float s1 = block_reduce(a, red);   // valid at t==0
    float s2 = block_reduce(b, red);

    // 2) exact medians (all threads get the value)
    float m1 = radix_select(W1, N1, K1, hist, s_pm, &s_kk);
    float m2 = radix_select(W2, N2, K2, hist, s_pm, &s_kk);

    // 3) q-sums over binarized values
    float acc1 = 0.f;
    for (int i = t; i < N1; i += 1024) {
        float bb = (W1[i] < m1) ? 0.f : 1.f;
        float dd = bb - am1[i];
        acc1 += dd * dd;
    }
    float acc2 = 0.f;
    for (int i = t; i < N2; i += 1024) {
        float bb = (W2[i] < m2) ? 0.f : 1.f;
        float dd = bb - am2[i];
        acc2 += dd * dd;
    }
    float t1 = block_reduce(acc1, red);
    float t2 = block_reduce(acc2, red);

    if (t == 0) {
        out[0] = (sqrtf(s1) + sqrtf(s2)) / 38400.f;
        out[1] = (sqrtf(t1) + sqrtf(t2)) / 384.f;
    }
}

extern "C" void kernel_launch(void* const* d_in, const int* in_sizes, int n_in,
                              void* d_out, int out_size, void* d_ws, size_t ws_size,
                              hipStream_t stream) {
    const float* c2  = (const float*)d_in[0];
    const float* c3  = (const float*)d_in[1];
    const float* vm1 = (const float*)d_in[2];
    const float* vm2 = (const float*)d_in[3];
    const float* am1 = (const float*)d_in[4];
    const float* am2 = (const float*)d_in[5];
    float* out = (float*)d_out;

    float* ws = (float*)d_ws;
    float* W1 = ws;                 // 12800
    float* W2 = ws + N1;            // 25600
    float* partial = ws + N1 + N2;  // 150

    gather_kernel<<<150, 256, 0, stream>>>(c2, c3, vm1, vm2, W1, W2, partial);
    finish_kernel<<<1, 1024, 0, stream>>>(W1, W2, partial, am1, am2, out);
}

// Round 2
// 290.734 us; speedup vs baseline: 1.1300x; 1.1300x over previous
//
#include <hip/hip_runtime.h>
#include <math.h>

// p = (||c2[:,:,7,7]-vmask1|| + ||c3[:,:,3,3]-vmask2||) / 38400
// m1,m2 = exact lower medians (k-th smallest, k=(n-1)/2)
// q = (||(tm1<m1?0:1)-amask1|| + ||(tm2<m2?0:1)-amask2||) / 384
//
// R2 strategy: 12-bit global histogram built during the gather (spread across
// 150 blocks -> no single-CU LDS-atomic serialization, which cost 126us in R1).
// Finisher: hierarchical hist scan -> tiny candidate set -> exact rank select.
//
// ws layout (4B units):
//   [0,12800)        W1 gathered tm1
//   [12800,38400)    W2 gathered tm2
//   [38400,38550)    per-block p partials
//   [38560,42656)    hist1 (4096 u32)
//   [42656,46752)    hist2 (4096 u32)

#define N1 12800
#define N2 25600
#define K1 6399
#define K2 12799
#define NBINS 4096
#define HSHIFT 20          // top 12 bits of the ordered key
#define CAP 4096           // candidate buffer (expected ~5-50 used)

__device__ __forceinline__ unsigned fkey(float f) {
    unsigned u = __float_as_uint(f);
    return (u & 0x80000000u) ? ~u : (u | 0x80000000u);
}
__device__ __forceinline__ float fkey_inv(unsigned u) {
    return (u & 0x80000000u) ? __uint_as_float(u & 0x7FFFFFFFu)
                             : __uint_as_float(~u);
}

__device__ __forceinline__ float block_reduce(float v, float* red) {
    const int lane = threadIdx.x & 63;
    const int wid  = threadIdx.x >> 6;
    const int nw   = (blockDim.x + 63) >> 6;
#pragma unroll
    for (int o = 32; o > 0; o >>= 1) v += __shfl_down(v, o, 64);
    if (lane == 0) red[wid] = v;
    __syncthreads();
    if (wid == 0) {
        v = (lane < nw) ? red[lane] : 0.f;
#pragma unroll
        for (int o = 8; o > 0; o >>= 1) v += __shfl_down(v, o, 64);
    }
    __syncthreads();
    return v;
}

// 150 blocks x 256. Blocks [0,50): tm1; [50,150): tm2.
// Gather + p partial sums + global 12-bit histogram (hist pre-zeroed).
__global__ __launch_bounds__(256) void gather_kernel(
    const float* __restrict__ c2, const float* __restrict__ c3,
    const float* __restrict__ vm1, const float* __restrict__ vm2,
    float* __restrict__ W1, float* __restrict__ W2,
    float* __restrict__ partial,
    unsigned* __restrict__ hist1, unsigned* __restrict__ hist2)
{
    __shared__ float red[16];
    int g = blockIdx.x * 256 + threadIdx.x;
    float d;
    if (g < N1) {
        float v = c2[(size_t)g * 3136 + 399];   // 7*56+7
        W1[g] = v;
        d = v - vm1[g];
        atomicAdd(&hist1[fkey(v) >> HSHIFT], 1u);
    } else {
        int j = g - N1;
        float v = c3[(size_t)j * 784 + 87];     // 3*28+3
        W2[j] = v;
        d = v - vm2[j];
        atomicAdd(&hist2[fkey(v) >> HSHIFT], 1u);
    }
    float ss = block_reduce(d * d, red);
    if (threadIdx.x == 0) partial[blockIdx.x] = ss;
}

__shared__ unsigned sh_h[NBINS];
__shared__ unsigned sh_csum[1024];
__shared__ unsigned sh_wsum[16];
__shared__ unsigned sh_cand[CAP];
__shared__ unsigned sh_bin;
__shared__ int sh_kk, sh_m;
__shared__ unsigned sh_res;

// Exact k-th smallest of W[0..n) using its prebuilt 12-bit histogram.
// All threads of the (single) block return the value.
__device__ float hist_select(const float* __restrict__ W, int n, int k,
                             const unsigned* __restrict__ histg)
{
    const int t = threadIdx.x;
    __syncthreads();
    // hist -> LDS
    for (int i = t; i < NBINS; i += 1024) sh_h[i] = histg[i];
    __syncthreads();
    // per-thread 4-bin chunk sum
    unsigned c = sh_h[4*t] + sh_h[4*t+1] + sh_h[4*t+2] + sh_h[4*t+3];
    sh_csum[t] = c;
    // per-wave sum
    unsigned wv = c;
#pragma unroll
    for (int o = 32; o > 0; o >>= 1) wv += __shfl_down(wv, o, 64);
    if ((t & 63) == 0) sh_wsum[t >> 6] = wv;
    __syncthreads();
    // thread 0: hierarchical serial scan (16 + 64 + 4 steps)
    if (t == 0) {
        int rem = k;
        int w = 0;
        for (; w < 16; ++w) { unsigned s = sh_wsum[w]; if ((unsigned)rem < s) break; rem -= (int)s; }
        int tc = w * 64;
        for (; tc < (w + 1) * 64; ++tc) { unsigned s = sh_csum[tc]; if ((unsigned)rem < s) break; rem -= (int)s; }
        int b = tc * 4;
        for (; b < tc * 4 + 4; ++b) { unsigned s = sh_h[b]; if ((unsigned)rem < s) break; rem -= (int)s; }
        sh_bin = (unsigned)b;
        sh_kk  = rem;
        sh_m   = 0;
    }
    __syncthreads();
    const unsigned bin = sh_bin;
    // collect candidates matching the 12-bit prefix
    for (int i = t; i < n; i += 1024) {
        unsigned u = fkey(W[i]);
        if ((u >> HSHIFT) == bin) {
            int p = atomicAdd(&sh_m, 1);
            if (p < CAP) sh_cand[p] = u;
        }
    }
    __syncthreads();
    const int m  = (sh_m < CAP) ? sh_m : CAP;
    const int kk = sh_kk;
    // exact rank selection among m candidates (m is tiny for this data)
    for (int i = t; i < m; i += 1024) {
        unsigned ui = sh_cand[i];
        int r = 0;
        for (int j = 0; j < m; ++j) {
            unsigned uj = sh_cand[j];
            r += (uj < ui) || (uj == ui && j < i);
        }
        if (r == kk) sh_res = ui;   // exactly one writer
    }
    __syncthreads();
    float res = fkey_inv(sh_res);
    __syncthreads();
    return res;
}

__global__ __launch_bounds__(1024) void finish_kernel(
    const float* __restrict__ W1, const float* __restrict__ W2,
    const float* __restrict__ partial,
    const unsigned* __restrict__ hist1, const unsigned* __restrict__ hist2,
    const float* __restrict__ am1, const float* __restrict__ am2,
    float* __restrict__ out)
{
    __shared__ float red[16];
    const int t = threadIdx.x;

    float a = (t < 50) ? partial[t] : 0.f;
    float b = (t >= 50 && t < 150) ? partial[t] : 0.f;
    float s1 = block_reduce(a, red);
    float s2 = block_reduce(b, red);

    float m1 = hist_select(W1, N1, K1, hist1);
    float m2 = hist_select(W2, N2, K2, hist2);

    float acc1 = 0.f;
    for (int i = t; i < N1; i += 1024) {
        float bb = (W1[i] < m1) ? 0.f : 1.f;
        float dd = bb - am1[i];
        acc1 += dd * dd;
    }
    float acc2 = 0.f;
    for (int i = t; i < N2; i += 1024) {
        float bb = (W2[i] < m2) ? 0.f : 1.f;
        float dd = bb - am2[i];
        acc2 += dd * dd;
    }
    float t1 = block_reduce(acc1, red);
    float t2 = block_reduce(acc2, red);

    if (t == 0) {
        out[0] = (sqrtf(s1) + sqrtf(s2)) / 38400.f;
        out[1] = (sqrtf(t1) + sqrtf(t2)) / 384.f;
    }
}

extern "C" void kernel_launch(void* const* d_in, const int* in_sizes, int n_in,
                              void* d_out, int out_size, void* d_ws, size_t ws_size,
                              hipStream_t stream) {
    const float* c2  = (const float*)d_in[0];
    const float* c3  = (const float*)d_in[1];
    const float* vm1 = (const float*)d_in[2];
    const float* vm2 = (const float*)d_in[3];
    const float* am1 = (const float*)d_in[4];
    const float* am2 = (const float*)d_in[5];
    float* out = (float*)d_out;

    float* ws = (float*)d_ws;
    float* W1      = ws;                        // 12800
    float* W2      = ws + N1;                   // 25600
    float* partial = ws + N1 + N2;              // 150
    unsigned* hist1 = (unsigned*)(ws + 38560);  // 4096
    unsigned* hist2 = hist1 + NBINS;            // 4096

    hipMemsetAsync(hist1, 0, 2 * NBINS * sizeof(unsigned), stream);
    gather_kernel<<<150, 256, 0, stream>>>(c2, c3, vm1, vm2, W1, W2, partial,
                                           hist1, hist2);
    finish_kernel<<<1, 1024, 0, stream>>>(W1, W2, partial, hist1, hist2,
                                          am1, am2, out);
}

// Round 3
// 284.446 us; speedup vs baseline: 1.1550x; 1.0221x over previous
//
#include <hip/hip_runtime.h>
#include <math.h>

// p = (||c2[:,:,7,7]-vmask1|| + ||c3[:,:,3,3]-vmask2||) / 38400
// m = exact lower median (k-th smallest, k=(n-1)/2) of each gathered slice
// q = (||(tm1<m1?0:1)-amask1|| + ||(tm2<m2?0:1)-amask2||) / 384
//
// R3: decompose q-sum = Sum(a^2) + Sum_{v>=m}(1-2a). Everything O(N) that
// touches masks runs in the 150-block gather; the single-block finisher only
// scans histograms + a tiny candidate set. Adjudicates whether R2's finisher
// was ~85us (hidden under the 93us harness fills) or already at the floor.
//
// ws layout (4B units):
//   [0,12800)        W1  gathered tm1
//   [12800,38400)    W2  gathered tm2
//   [38400,38550)    partialP  per-block (v-vm)^2 sums
//   [38560,38710)    partialA2 per-block a^2 sums
//   [38720,42816)    hist1 (4096 u32)   [zeroed by memset]
//   [42816,46912)    hist2 (4096 u32)   [zeroed]
//   [46912,51008)    T1 (4096 f32, Sum(1-2a) per bin)  [zeroed]
//   [51008,55104)    T2 (4096 f32)                     [zeroed]

#define N1 12800
#define N2 25600
#define K1 6399
#define K2 12799
#define NBINS 4096
#define HSHIFT 20
#define CAP 1024

__device__ __forceinline__ unsigned fkey(float f) {
    unsigned u = __float_as_uint(f);
    return (u & 0x80000000u) ? ~u : (u | 0x80000000u);
}

__device__ __forceinline__ float block_reduce(float v, float* red) {
    const int lane = threadIdx.x & 63;
    const int wid  = threadIdx.x >> 6;
    const int nw   = (blockDim.x + 63) >> 6;
#pragma unroll
    for (int o = 32; o > 0; o >>= 1) v += __shfl_down(v, o, 64);
    if (lane == 0) red[wid] = v;
    __syncthreads();
    if (wid == 0) {
        v = (lane < nw) ? red[lane] : 0.f;
#pragma unroll
        for (int o = 8; o > 0; o >>= 1) v += __shfl_down(v, o, 64);
    }
    __syncthreads();
    return v;
}

// 150 blocks x 256. Blocks [0,50): tm1; [50,150): tm2.
__global__ __launch_bounds__(256) void gather_kernel(
    const float* __restrict__ c2, const float* __restrict__ c3,
    const float* __restrict__ vm1, const float* __restrict__ vm2,
    const float* __restrict__ am1, const float* __restrict__ am2,
    float* __restrict__ W1, float* __restrict__ W2,
    float* __restrict__ partialP, float* __restrict__ partialA2,
    unsigned* __restrict__ hist1, unsigned* __restrict__ hist2,
    float* __restrict__ T1, float* __restrict__ T2)
{
    __shared__ float red[16];
    int g = blockIdx.x * 256 + threadIdx.x;
    float d, a;
    if (g < N1) {
        float v = c2[(size_t)g * 3136 + 399];   // 7*56+7
        W1[g] = v;
        d = v - vm1[g];
        a = am1[g];
        unsigned b = fkey(v) >> HSHIFT;
        atomicAdd(&hist1[b], 1u);
        atomicAdd(&T1[b], 1.f - 2.f * a);
    } else {
        int j = g - N1;
        float v = c3[(size_t)j * 784 + 87];     // 3*28+3
        W2[j] = v;
        d = v - vm2[j];
        a = am2[j];
        unsigned b = fkey(v) >> HSHIFT;
        atomicAdd(&hist2[b], 1u);
        atomicAdd(&T2[b], 1.f - 2.f * a);
    }
    float pss = block_reduce(d * d, red);
    float ass = block_reduce(a * a, red);
    if (threadIdx.x == 0) {
        partialP[blockIdx.x]  = pss;
        partialA2[blockIdx.x] = ass;
    }
}

// Find bin containing rank k, and residual rank within it. All-thread entry.
__device__ void hist_scan(const unsigned* __restrict__ histg, int k,
                          unsigned* sh_h, unsigned* sh_csum, unsigned* sh_wsum,
                          int* sh_bin, int* sh_kk)
{
    const int t = threadIdx.x;
    __syncthreads();
    for (int i = t; i < NBINS; i += 1024) sh_h[i] = histg[i];
    __syncthreads();
    unsigned c = sh_h[4*t] + sh_h[4*t+1] + sh_h[4*t+2] + sh_h[4*t+3];
    sh_csum[t] = c;
    unsigned wv = c;
#pragma unroll
    for (int o = 32; o > 0; o >>= 1) wv += __shfl_down(wv, o, 64);
    if ((t & 63) == 0) sh_wsum[t >> 6] = wv;
    __syncthreads();
    if (t == 0) {
        int rem = k;
        int w = 0;
        for (; w < 16; ++w) { unsigned s = sh_wsum[w]; if ((unsigned)rem < s) break; rem -= (int)s; }
        int tc = w * 64;
        for (; tc < (w + 1) * 64; ++tc) { unsigned s = sh_csum[tc]; if ((unsigned)rem < s) break; rem -= (int)s; }
        int b = tc * 4;
        for (; b < tc * 4 + 4; ++b) { unsigned s = sh_h[b]; if ((unsigned)rem < s) break; rem -= (int)s; }
        *sh_bin = b;
        *sh_kk  = rem;
    }
    __syncthreads();
}

// Collect candidates in `bin`, exact-rank-select key, return boundary
// correction Sum_{cand u>=u_m}(1-2a) in *corr (valid at t==0).
__device__ void cand_select(const float* __restrict__ W, int n,
                            const float* __restrict__ am,
                            int bin, int kk,
                            unsigned* cand_u, float* cand_a,
                            int* sh_m, unsigned* sh_res, float* red,
                            float* corr)
{
    const int t = threadIdx.x;
    if (t == 0) *sh_m = 0;
    __syncthreads();
    for (int i = t; i < n; i += 1024) {
        unsigned u = fkey(W[i]);
        if ((int)(u >> HSHIFT) == bin) {
            int p = atomicAdd(sh_m, 1);
            if (p < CAP) { cand_u[p] = u; cand_a[p] = am[i]; }
        }
    }
    __syncthreads();
    const int m = (*sh_m < CAP) ? *sh_m : CAP;
    for (int i = t; i < m; i += 1024) {
        unsigned ui = cand_u[i];
        int r = 0;
        for (int j = 0; j < m; ++j) {
            unsigned uj = cand_u[j];
            r += (uj < ui) || (uj == ui && j < i);
        }
        if (r == kk) *sh_res = ui;   // exactly one writer
    }
    __syncthreads();
    const unsigned um = *sh_res;
    float cc = 0.f;
    for (int i = t; i < m; i += 1024)
        if (cand_u[i] >= um) cc += 1.f - 2.f * cand_a[i];
    float tot = block_reduce(cc, red);
    if (t == 0) *corr = tot;
    __syncthreads();
}

__global__ __launch_bounds__(1024) void finish_kernel(
    const float* __restrict__ W1, const float* __restrict__ W2,
    const float* __restrict__ partialP, const float* __restrict__ partialA2,
    const unsigned* __restrict__ hist1, const unsigned* __restrict__ hist2,
    const float* __restrict__ T1, const float* __restrict__ T2,
    const float* __restrict__ am1, const float* __restrict__ am2,
    float* __restrict__ out)
{
    __shared__ unsigned sh_h[NBINS];
    __shared__ unsigned sh_csum[1024];
    __shared__ unsigned sh_wsum[16];
    __shared__ unsigned cand_u[CAP];
    __shared__ float    cand_a[CAP];
    __shared__ float    red[16];
    __shared__ int sh_bin, sh_kk, sh_m;
    __shared__ unsigned sh_res;
    __shared__ float sh_corr1, sh_corr2;

    const int t = threadIdx.x;

    // partial reductions (valid at t==0)
    float s1  = block_reduce((t < 50) ? partialP[t] : 0.f, red);
    float s2  = block_reduce((t >= 50 && t < 150) ? partialP[t] : 0.f, red);
    float a21 = block_reduce((t < 50) ? partialA2[t] : 0.f, red);
    float a22 = block_reduce((t >= 50 && t < 150) ? partialA2[t] : 0.f, red);

    // --- median 1 ---
    hist_scan(hist1, K1, sh_h, sh_csum, sh_wsum, &sh_bin, &sh_kk);
    int b1 = sh_bin, kk1 = sh_kk;
    float sv = 0.f;
#pragma unroll
    for (int j = 0; j < 4; ++j) { int b = 4*t + j; if (b > b1) sv += T1[b]; }
    float suff1 = block_reduce(sv, red);
    cand_select(W1, N1, am1, b1, kk1, cand_u, cand_a, &sh_m, &sh_res, red, &sh_corr1);

    // --- median 2 ---
    hist_scan(hist2, K2, sh_h, sh_csum, sh_wsum, &sh_bin, &sh_kk);
    int b2 = sh_bin, kk2 = sh_kk;
    sv = 0.f;
#pragma unroll
    for (int j = 0; j < 4; ++j) { int b = 4*t + j; if (b > b2) sv += T2[b]; }
    float suff2 = block_reduce(sv, red);
    cand_select(W2, N2, am2, b2, kk2, cand_u, cand_a, &sh_m, &sh_res, red, &sh_corr2);

    if (t == 0) {
        float q1 = a21 + suff1 + sh_corr1;
        float q2 = a22 + suff2 + sh_corr2;
        out[0] = (sqrtf(s1) + sqrtf(s2)) / 38400.f;
        out[1] = (sqrtf(q1) + sqrtf(q2)) / 384.f;
    }
}

extern "C" void kernel_launch(void* const* d_in, const int* in_sizes, int n_in,
                              void* d_out, int out_size, void* d_ws, size_t ws_size,
                              hipStream_t stream) {
    const float* c2  = (const float*)d_in[0];
    const float* c3  = (const float*)d_in[1];
    const float* vm1 = (const float*)d_in[2];
    const float* vm2 = (const float*)d_in[3];
    const float* am1 = (const float*)d_in[4];
    const float* am2 = (const float*)d_in[5];
    float* out = (float*)d_out;

    float* ws = (float*)d_ws;
    float* W1        = ws;                         // 12800
    float* W2        = ws + N1;                    // 25600
    float* partialP  = ws + 38400;                 // 150
    float* partialA2 = ws + 38560;                 // 150
    unsigned* hist1  = (unsigned*)(ws + 38720);    // 4096
    unsigned* hist2  = hist1 + NBINS;              // 4096
    float* T1        = (float*)(hist2 + NBINS);    // 4096
    float* T2        = T1 + NBINS;                 // 4096

    // zero hist1,hist2,T1,T2 (contiguous 64 KB)
    hipMemsetAsync(hist1, 0, 4 * NBINS * sizeof(unsigned), stream);
    gather_kernel<<<150, 256, 0, stream>>>(c2, c3, vm1, vm2, am1, am2,
                                           W1, W2, partialP, partialA2,
                                           hist1, hist2, T1, T2);
    finish_kernel<<<1, 1024, 0, stream>>>(W1, W2, partialP, partialA2,
                                          hist1, hist2, T1, T2, am1, am2, out);
}